// Round 1
// baseline (394.556 us; speedup 1.0000x reference)
//
#include <hip/hip_runtime.h>
#include <hip/hip_bf16.h>
#include <math.h>

typedef __attribute__((ext_vector_type(8))) short bf16x8;
typedef __attribute__((ext_vector_type(4))) float f32x4;

#define NB 4096
#define ND 1024
#define INV_T 14.2857142857142857f   // 1/0.07

__device__ inline unsigned short f2bf(float x) {
    __hip_bfloat16 h = __float2bfloat16(x);
    return *reinterpret_cast<unsigned short*>(&h);
}

// ---------------- kernel 0: L2-normalize rows, cast to bf16 -----------------
__global__ __launch_bounds__(256) void norm_kernel(
        const float* __restrict__ M, const float* __restrict__ P,
        __hip_bfloat16* __restrict__ Mn, __hip_bfloat16* __restrict__ Pn) {
    int row = blockIdx.x & (NB - 1);
    const float* src = (blockIdx.x < NB) ? M : P;
    __hip_bfloat16* dst = (blockIdx.x < NB) ? Mn : Pn;
    int tid = threadIdx.x;
    float4 v = ((const float4*)(src + (size_t)row * ND))[tid];
    float ss = v.x * v.x + v.y * v.y + v.z * v.z + v.w * v.w;
    for (int off = 32; off; off >>= 1) ss += __shfl_down(ss, off);
    __shared__ float red[4];
    int lane = tid & 63, w = tid >> 6;
    if (lane == 0) red[w] = ss;
    __syncthreads();
    float rn = rsqrtf(red[0] + red[1] + red[2] + red[3]);
    ushort4 o;
    o.x = f2bf(v.x * rn); o.y = f2bf(v.y * rn);
    o.z = f2bf(v.z * rn); o.w = f2bf(v.w * rn);
    *(ushort4*)((unsigned short*)dst + (size_t)row * ND + tid * 4) = o;
}

// ---------------- kernel 1: per-row mask codes ------------------------------
__global__ __launch_bounds__(256) void key_kernel(
        const int* __restrict__ labels, const int* __restrict__ sm,
        const int* __restrict__ sp, int* __restrict__ code) {
    int i = blockIdx.x * 256 + threadIdx.x;
    if (i < NB) {
        int l = labels[i];
        code[i] = (l == 0) ? 0x40000000 : (1 + l + (sm[i] << 8) + (sp[i] << 16));
    }
}

// ---------------- kernel 2: row sums of masked clinical similarity ----------
__global__ __launch_bounds__(256) void rowsum_kernel(
        const float* __restrict__ cs, const int* __restrict__ code,
        float* __restrict__ invr, float* __restrict__ flag) {
    int i = blockIdx.x;
    int ci = code[i];
    int tid = threadIdx.x;
    const float4* row = (const float4*)(cs + (size_t)i * NB);
    const int4* c4 = (const int4*)code;
    float s = 0.f;
    for (int t = tid; t < NB / 4; t += 256) {
        float4 v = row[t];
        int4 cj = c4[t];
        int j = t * 4;
        if (cj.x == ci && j + 0 != i) s += v.x;
        if (cj.y == ci && j + 1 != i) s += v.y;
        if (cj.z == ci && j + 2 != i) s += v.z;
        if (cj.w == ci && j + 3 != i) s += v.w;
    }
    for (int off = 32; off; off >>= 1) s += __shfl_down(s, off);
    __shared__ float red[4];
    int lane = tid & 63, w = tid >> 6;
    if (lane == 0) red[w] = s;
    __syncthreads();
    if (tid == 0) {
        float tot = red[0] + red[1] + red[2] + red[3];
        invr[i] = (tot > 0.f) ? 1.f / tot : 0.f;
        flag[i] = (tot > 0.f) ? 1.f : 0.f;
    }
}

// ---------------- kernel 3: bf16 MFMA GEMM with fused softmax/loss epilogue -
// MODE 0: S1 = Mn Pn^T  -> rowsum1, colsum1, dots[0] (w.S1), dots[1] (w^T.S1)
// MODE 1: S3 = Mn Mn^T  -> rowsum3, dots[2]
// MODE 2: S4 = Pn Pn^T  -> rowsum4, dots[3]
#define LDK 72  // 64 + 8 bf16 pad (keeps 16B alignment, breaks bank conflicts)

template <int MODE>
__global__ __launch_bounds__(256, 2) void gemm_kernel(
        const __hip_bfloat16* __restrict__ A, const __hip_bfloat16* __restrict__ Bm,
        const float* __restrict__ cs, const int* __restrict__ code,
        const float* __restrict__ invr,
        float* __restrict__ rowsum, float* __restrict__ colsum,
        float* __restrict__ dots) {
    __shared__ __hip_bfloat16 sA[128 * LDK];
    __shared__ __hip_bfloat16 sB[128 * LDK];
    __shared__ int sCodeR[128], sCodeC[128];
    __shared__ float sInvR[128], sInvC[128];

    int tid = threadIdx.x;
    int lane = tid & 63, wid = tid >> 6;
    int wm = wid >> 1, wn = wid & 1;
    int lr = lane & 15, lg = lane >> 4;
    size_t rowBase = (size_t)blockIdx.y * 128;
    size_t colBase = (size_t)blockIdx.x * 128;

    f32x4 acc[4][4] = {};

    for (int kt = 0; kt < 16; ++kt) {
        int k0 = kt * 64;
        __syncthreads();
#pragma unroll
        for (int c = 0; c < 4; ++c) {
            int idx = tid + c * 256;
            int r = idx >> 3, col = (idx & 7) * 8;
            *(int4*)&sA[r * LDK + col] =
                *(const int4*)(A + (rowBase + r) * ND + k0 + col);
            *(int4*)&sB[r * LDK + col] =
                *(const int4*)(Bm + (colBase + r) * ND + k0 + col);
        }
        __syncthreads();
#pragma unroll
        for (int ks = 0; ks < 2; ++ks) {
            bf16x8 av[4], bv[4];
#pragma unroll
            for (int m = 0; m < 4; ++m)
                av[m] = *(const bf16x8*)&sA[(wm * 64 + m * 16 + lr) * LDK + ks * 32 + lg * 8];
#pragma unroll
            for (int n = 0; n < 4; ++n)
                bv[n] = *(const bf16x8*)&sB[(wn * 64 + n * 16 + lr) * LDK + ks * 32 + lg * 8];
#pragma unroll
            for (int m = 0; m < 4; ++m)
#pragma unroll
                for (int n = 0; n < 4; ++n)
                    acc[m][n] = __builtin_amdgcn_mfma_f32_16x16x32_bf16(
                        av[m], bv[n], acc[m][n], 0, 0, 0);
        }
    }

    // ---- epilogue ----
    __syncthreads();
    if (tid < 128) {
        sCodeR[tid] = code[rowBase + tid];
        sInvR[tid] = invr[rowBase + tid];
        sCodeC[tid] = code[colBase + tid];
        if (MODE == 0) sInvC[tid] = invr[colBase + tid];
    }
    __syncthreads();

    float d1 = 0.f, d2 = 0.f;
    float cexp[4] = {0.f, 0.f, 0.f, 0.f};
#pragma unroll
    for (int m = 0; m < 4; ++m) {
        float rexp[4] = {0.f, 0.f, 0.f, 0.f};
#pragma unroll
        for (int n = 0; n < 4; ++n) {
            int ljc = wn * 64 + n * 16 + lr;
            int gj = (int)colBase + ljc;
            int cj = sCodeC[ljc];
#pragma unroll
            for (int r = 0; r < 4; ++r) {
                int lir = wm * 64 + m * 16 + lg * 4 + r;
                int gi = (int)rowBase + lir;
                float sim = acc[m][n][r] * INV_T;
                float e = __expf(sim - INV_T);
                rexp[r] += e;
                if (MODE == 0) cexp[n] += e;
                if (sCodeR[lir] == cj && gi != gj) {
                    float c_ij = cs[(size_t)gi * NB + gj];
                    d1 += c_ij * sInvR[lir] * sim;
                    if (MODE == 0) {
                        float c_ji = cs[(size_t)gj * NB + gi];
                        d2 += c_ji * sInvC[ljc] * sim;
                    }
                }
            }
        }
#pragma unroll
        for (int r = 0; r < 4; ++r) {
            float v = rexp[r];
            v += __shfl_xor(v, 1); v += __shfl_xor(v, 2);
            v += __shfl_xor(v, 4); v += __shfl_xor(v, 8);
            if (lr == 0)
                atomicAdd(&rowsum[rowBase + wm * 64 + m * 16 + lg * 4 + r], v);
        }
    }
    if (MODE == 0) {
#pragma unroll
        for (int n = 0; n < 4; ++n) {
            float v = cexp[n];
            v += __shfl_xor(v, 16); v += __shfl_xor(v, 32);
            if (lg == 0)
                atomicAdd(&colsum[colBase + wn * 64 + n * 16 + lr], v);
        }
    }
    for (int off = 32; off; off >>= 1) d1 += __shfl_xor(d1, off);
    if (MODE == 0)
        for (int off = 32; off; off >>= 1) d2 += __shfl_xor(d2, off);
    if (lane == 0) {
        if (MODE == 0) {
            atomicAdd(&dots[0], d1);
            atomicAdd(&dots[1], d2);
        } else if (MODE == 1) {
            atomicAdd(&dots[2], d1);
        } else {
            atomicAdd(&dots[3], d1);
        }
    }
}

// ---------------- kernel 4: finalize --------------------------------------
__global__ __launch_bounds__(256) void finalize_kernel(
        const float* __restrict__ rowsum1, const float* __restrict__ colsum1,
        const float* __restrict__ rowsum3, const float* __restrict__ rowsum4,
        const float* __restrict__ flag, const float* __restrict__ dots,
        float* __restrict__ out) {
    int tid = threadIdx.x;
    float l = 0.f;
    for (int i = tid; i < NB; i += 256) {
        if (flag[i] != 0.f) {
            l += 4.f * INV_T + logf(rowsum1[i]) + logf(colsum1[i]) +
                 logf(rowsum3[i]) + logf(rowsum4[i]);
        }
    }
    for (int off = 32; off; off >>= 1) l += __shfl_down(l, off);
    __shared__ float red[4];
    int lane = tid & 63, w = tid >> 6;
    if (lane == 0) red[w] = l;
    __syncthreads();
    if (tid == 0) {
        float L = red[0] + red[1] + red[2] + red[3];
        float dt = dots[0] + dots[1] + dots[2] + dots[3];
        out[0] = (L - dt) / (4.0f * (float)NB);
    }
}

extern "C" void kernel_launch(void* const* d_in, const int* in_sizes, int n_in,
                              void* d_out, int out_size, void* d_ws, size_t ws_size,
                              hipStream_t stream) {
    const float* M = (const float*)d_in[0];
    const float* P = (const float*)d_in[1];
    const int* labels = (const int*)d_in[2];
    const int* sm = (const int*)d_in[3];
    const int* sp = (const int*)d_in[4];
    const float* cs = (const float*)d_in[5];
    float* out = (float*)d_out;

    char* ws = (char*)d_ws;
    __hip_bfloat16* Mn = (__hip_bfloat16*)ws;
    __hip_bfloat16* Pn = (__hip_bfloat16*)(ws + (size_t)8 * 1024 * 1024);
    char* p = ws + (size_t)16 * 1024 * 1024;
    int* code = (int*)p;        p += 16384;
    float* invr = (float*)p;    p += 16384;
    float* flag = (float*)p;    p += 16384;
    float* rowsum1 = (float*)p; p += 16384;
    float* colsum1 = (float*)p; p += 16384;
    float* rowsum3 = (float*)p; p += 16384;
    float* rowsum4 = (float*)p; p += 16384;
    float* dots = (float*)p;

    // zero accumulators (rowsum1..dots are contiguous)
    hipMemsetAsync(rowsum1, 0, 4 * 16384 + 256, stream);

    norm_kernel<<<2 * NB, 256, 0, stream>>>(M, P, Mn, Pn);
    key_kernel<<<NB / 256, 256, 0, stream>>>(labels, sm, sp, code);
    rowsum_kernel<<<NB, 256, 0, stream>>>(cs, code, invr, flag);

    dim3 g(32, 32);
    gemm_kernel<0><<<g, 256, 0, stream>>>(Mn, Pn, cs, code, invr, rowsum1, colsum1, dots);
    gemm_kernel<1><<<g, 256, 0, stream>>>(Mn, Mn, cs, code, invr, rowsum3, nullptr, dots);
    gemm_kernel<2><<<g, 256, 0, stream>>>(Pn, Pn, cs, code, invr, rowsum4, nullptr, dots);

    finalize_kernel<<<1, 256, 0, stream>>>(rowsum1, colsum1, rowsum3, rowsum4,
                                           flag, dots, out);
}

// Round 2
// 358.417 us; speedup vs baseline: 1.1008x; 1.1008x over previous
//
#include <hip/hip_runtime.h>
#include <hip/hip_bf16.h>
#include <math.h>

typedef __attribute__((ext_vector_type(8))) short bf16x8;
typedef __attribute__((ext_vector_type(4))) float f32x4;

#define NB 4096
#define ND 1024
#define INV_T 14.2857142857142857f   // 1/0.07

__device__ inline unsigned short f2bf(float x) {
    __hip_bfloat16 h = __float2bfloat16(x);
    return *reinterpret_cast<unsigned short*>(&h);
}

__device__ inline void gload16(const void* g, void* l) {
    __builtin_amdgcn_global_load_lds(
        (const __attribute__((address_space(1))) void*)g,
        (__attribute__((address_space(3))) void*)l, 16, 0, 0);
}

// ---------------- kernel 0: L2-normalize rows, cast to bf16 -----------------
__global__ __launch_bounds__(256) void norm_kernel(
        const float* __restrict__ M, const float* __restrict__ P,
        __hip_bfloat16* __restrict__ Mn, __hip_bfloat16* __restrict__ Pn) {
    int row = blockIdx.x & (NB - 1);
    const float* src = (blockIdx.x < NB) ? M : P;
    __hip_bfloat16* dst = (blockIdx.x < NB) ? Mn : Pn;
    int tid = threadIdx.x;
    float4 v = ((const float4*)(src + (size_t)row * ND))[tid];
    float ss = v.x * v.x + v.y * v.y + v.z * v.z + v.w * v.w;
    for (int off = 32; off; off >>= 1) ss += __shfl_down(ss, off);
    __shared__ float red[4];
    int lane = tid & 63, w = tid >> 6;
    if (lane == 0) red[w] = ss;
    __syncthreads();
    float rn = rsqrtf(red[0] + red[1] + red[2] + red[3]);
    ushort4 o;
    o.x = f2bf(v.x * rn); o.y = f2bf(v.y * rn);
    o.z = f2bf(v.z * rn); o.w = f2bf(v.w * rn);
    *(ushort4*)((unsigned short*)dst + (size_t)row * ND + tid * 4) = o;
}

// ---------------- kernel 1: per-row mask codes ------------------------------
__global__ __launch_bounds__(256) void key_kernel(
        const int* __restrict__ labels, const int* __restrict__ sm,
        const int* __restrict__ sp, int* __restrict__ code) {
    int i = blockIdx.x * 256 + threadIdx.x;
    if (i < NB) {
        int l = labels[i];
        code[i] = (l == 0) ? 0x40000000 : (1 + l + (sm[i] << 8) + (sp[i] << 16));
    }
}

// ---------------- kernel 2: row sums of masked clinical similarity ----------
__global__ __launch_bounds__(256) void rowsum_kernel(
        const float* __restrict__ cs, const int* __restrict__ code,
        float* __restrict__ invr, float* __restrict__ flag) {
    int i = blockIdx.x;
    int ci = code[i];
    int tid = threadIdx.x;
    const float4* row = (const float4*)(cs + (size_t)i * NB);
    const int4* c4 = (const int4*)code;
    float s = 0.f;
    for (int t = tid; t < NB / 4; t += 256) {
        float4 v = row[t];
        int4 cj = c4[t];
        int j = t * 4;
        if (cj.x == ci && j + 0 != i) s += v.x;
        if (cj.y == ci && j + 1 != i) s += v.y;
        if (cj.z == ci && j + 2 != i) s += v.z;
        if (cj.w == ci && j + 3 != i) s += v.w;
    }
    for (int off = 32; off; off >>= 1) s += __shfl_down(s, off);
    __shared__ float red[4];
    int lane = tid & 63, w = tid >> 6;
    if (lane == 0) red[w] = s;
    __syncthreads();
    if (tid == 0) {
        float tot = red[0] + red[1] + red[2] + red[3];
        invr[i] = (tot > 0.f) ? 1.f / tot : 0.f;
        flag[i] = (tot > 0.f) ? 1.f : 0.f;
    }
}

// ---------------- kernel 3: bf16 MFMA GEMM with fused softmax/loss epilogue -
// MODE 0: S1 = Mn Pn^T, full 32x32 grid.
//         rexp->rowsum, cexp->colsum, d1->dotA (w.S), d2->dotB (w^T.S)
// MODE 1/2: symmetric S = A A^T, upper-triangle grid (528 blocks).
//         off-diag: rexp->rowsum[row], cexp->rowsum[col], d1+d2->dotA
//         diag:     rexp->rowsum[row], d1->dotA
template <int MODE>
__global__ __launch_bounds__(256, 2) void gemm_kernel(
        const __hip_bfloat16* __restrict__ A, const __hip_bfloat16* __restrict__ Bm,
        const float* __restrict__ cs, const int* __restrict__ code,
        const float* __restrict__ invr,
        float* __restrict__ rowsum, float* __restrict__ colsum,
        float* __restrict__ dotA, float* __restrict__ dotB) {
    __shared__ __hip_bfloat16 sA[128 * 64];
    __shared__ __hip_bfloat16 sB[128 * 64];
    __shared__ int sCodeR[128], sCodeC[128];
    __shared__ float sInvR[128], sInvC[128];

    int tid = threadIdx.x;
    int lane = tid & 63, wid = tid >> 6;
    int wm = wid >> 1, wn = wid & 1;
    int lr = lane & 15, lg = lane >> 4;

    int bi, bj;
    if (MODE == 0) {
        bi = blockIdx.y; bj = blockIdx.x;
    } else {
        int t = blockIdx.x;
        bi = 0;
        while (t >= 32 - bi) { t -= 32 - bi; ++bi; }
        bj = bi + t;
    }
    bool offdiag = (MODE != 0) && (bi != bj);
    bool doCol = (MODE == 0) || offdiag;
    size_t rowBase = (size_t)bi * 128;
    size_t colBase = (size_t)bj * 128;

    // per-lane global staging address components (row within tile, 16B chunk)
    int srow = (wid * 4) * 8 + (lane >> 3);  // rows covered: wave w -> 4 chunks
    int schunk = (lane & 7) * 8;             // bf16 elements

    f32x4 acc[4][4] = {};

    for (int kt = 0; kt < 16; ++kt) {
        int k0 = kt * 64;
        // stage next tile: each wave issues 4 A-loads + 4 B-loads of 1 KB
#pragma unroll
        for (int c = 0; c < 4; ++c) {
            int q = wid * 4 + c;            // 0..15, wave-uniform
            int row = srow + c * 8;
            gload16(A + (rowBase + row) * ND + k0 + schunk, &sA[q * 512]);
            gload16(Bm + (colBase + row) * ND + k0 + schunk, &sB[q * 512]);
        }
        __syncthreads();   // drains vmcnt + lgkm before reads
#pragma unroll
        for (int ks = 0; ks < 2; ++ks) {
            bf16x8 av[4], bv[4];
#pragma unroll
            for (int m = 0; m < 4; ++m)
                av[m] = *(const bf16x8*)&sA[(wm * 64 + m * 16 + lr) * 64 + ks * 32 + lg * 8];
#pragma unroll
            for (int n = 0; n < 4; ++n)
                bv[n] = *(const bf16x8*)&sB[(wn * 64 + n * 16 + lr) * 64 + ks * 32 + lg * 8];
#pragma unroll
            for (int m = 0; m < 4; ++m)
#pragma unroll
                for (int n = 0; n < 4; ++n)
                    acc[m][n] = __builtin_amdgcn_mfma_f32_16x16x32_bf16(
                        av[m], bv[n], acc[m][n], 0, 0, 0);
        }
        __syncthreads();   // protect LDS before next stage overwrites
    }

    // ---- epilogue ----
    if (tid < 128) {
        sCodeR[tid] = code[rowBase + tid];
        sInvR[tid] = invr[rowBase + tid];
        sCodeC[tid] = code[colBase + tid];
        sInvC[tid] = invr[colBase + tid];
    }
    __syncthreads();

    float d1 = 0.f, d2 = 0.f;
    float cexp[4] = {0.f, 0.f, 0.f, 0.f};
#pragma unroll
    for (int m = 0; m < 4; ++m) {
        float rexp[4] = {0.f, 0.f, 0.f, 0.f};
#pragma unroll
        for (int n = 0; n < 4; ++n) {
            int ljc = wn * 64 + n * 16 + lr;
            int gj = (int)colBase + ljc;
            int cj = sCodeC[ljc];
#pragma unroll
            for (int r = 0; r < 4; ++r) {
                int lir = wm * 64 + m * 16 + lg * 4 + r;
                int gi = (int)rowBase + lir;
                float sim = acc[m][n][r] * INV_T;
                float e = __expf(sim - INV_T);
                rexp[r] += e;
                cexp[n] += e;
                if (sCodeR[lir] == cj && gi != gj) {
                    float c_ij = cs[(size_t)gi * NB + gj];
                    d1 += c_ij * sInvR[lir] * sim;
                    float c_ji = cs[(size_t)gj * NB + gi];
                    d2 += c_ji * sInvC[ljc] * sim;
                }
            }
        }
#pragma unroll
        for (int r = 0; r < 4; ++r) {
            float v = rexp[r];
            v += __shfl_xor(v, 1); v += __shfl_xor(v, 2);
            v += __shfl_xor(v, 4); v += __shfl_xor(v, 8);
            if (lr == 0)
                atomicAdd(&rowsum[rowBase + wm * 64 + m * 16 + lg * 4 + r], v);
        }
    }
    if (doCol) {
        float* ctgt = (MODE == 0) ? colsum : rowsum;
#pragma unroll
        for (int n = 0; n < 4; ++n) {
            float v = cexp[n];
            v += __shfl_xor(v, 16); v += __shfl_xor(v, 32);
            if (lg == 0)
                atomicAdd(&ctgt[colBase + wn * 64 + n * 16 + lr], v);
        }
    }
    float dtot = d1 + ((MODE != 0 && offdiag) ? d2 : 0.f);
    for (int off = 32; off; off >>= 1) {
        dtot += __shfl_xor(dtot, off);
        if (MODE == 0) d2 += __shfl_xor(d2, off);
    }
    if (lane == 0) {
        atomicAdd(dotA, dtot);
        if (MODE == 0) atomicAdd(dotB, d2);
    }
}

// ---------------- kernel 4: finalize --------------------------------------
__global__ __launch_bounds__(256) void finalize_kernel(
        const float* __restrict__ rowsum1, const float* __restrict__ colsum1,
        const float* __restrict__ rowsum3, const float* __restrict__ rowsum4,
        const float* __restrict__ flag, const float* __restrict__ dots,
        float* __restrict__ out) {
    int tid = threadIdx.x;
    float l = 0.f;
    for (int i = tid; i < NB; i += 256) {
        if (flag[i] != 0.f) {
            l += 4.f * INV_T + logf(rowsum1[i]) + logf(colsum1[i]) +
                 logf(rowsum3[i]) + logf(rowsum4[i]);
        }
    }
    for (int off = 32; off; off >>= 1) l += __shfl_down(l, off);
    __shared__ float red[4];
    int lane = tid & 63, w = tid >> 6;
    if (lane == 0) red[w] = l;
    __syncthreads();
    if (tid == 0) {
        float L = red[0] + red[1] + red[2] + red[3];
        float dt = dots[0] + dots[1] + dots[2] + dots[3];
        out[0] = (L - dt) / (4.0f * (float)NB);
    }
}

extern "C" void kernel_launch(void* const* d_in, const int* in_sizes, int n_in,
                              void* d_out, int out_size, void* d_ws, size_t ws_size,
                              hipStream_t stream) {
    const float* M = (const float*)d_in[0];
    const float* P = (const float*)d_in[1];
    const int* labels = (const int*)d_in[2];
    const int* sm = (const int*)d_in[3];
    const int* sp = (const int*)d_in[4];
    const float* cs = (const float*)d_in[5];
    float* out = (float*)d_out;

    char* ws = (char*)d_ws;
    __hip_bfloat16* Mn = (__hip_bfloat16*)ws;
    __hip_bfloat16* Pn = (__hip_bfloat16*)(ws + (size_t)8 * 1024 * 1024);
    char* p = ws + (size_t)16 * 1024 * 1024;
    int* code = (int*)p;        p += 16384;
    float* invr = (float*)p;    p += 16384;
    float* flag = (float*)p;    p += 16384;
    float* rowsum1 = (float*)p; p += 16384;
    float* colsum1 = (float*)p; p += 16384;
    float* rowsum3 = (float*)p; p += 16384;
    float* rowsum4 = (float*)p; p += 16384;
    float* dots = (float*)p;

    // zero accumulators (rowsum1..colsum1..rowsum3..rowsum4..dots contiguous)
    hipMemsetAsync(rowsum1, 0, 4 * 16384 + 256, stream);

    norm_kernel<<<2 * NB, 256, 0, stream>>>(M, P, Mn, Pn);
    key_kernel<<<NB / 256, 256, 0, stream>>>(labels, sm, sp, code);
    rowsum_kernel<<<NB, 256, 0, stream>>>(cs, code, invr, flag);

    dim3 g(32, 32);
    gemm_kernel<0><<<g, 256, 0, stream>>>(Mn, Pn, cs, code, invr,
                                          rowsum1, colsum1, &dots[0], &dots[1]);
    gemm_kernel<1><<<528, 256, 0, stream>>>(Mn, Mn, cs, code, invr,
                                            rowsum3, nullptr, &dots[2], nullptr);
    gemm_kernel<2><<<528, 256, 0, stream>>>(Pn, Pn, cs, code, invr,
                                            rowsum4, nullptr, &dots[3], nullptr);

    finalize_kernel<<<1, 256, 0, stream>>>(rowsum1, colsum1, rowsum3, rowsum4,
                                           flag, dots, out);
}

// Round 3
// 282.081 us; speedup vs baseline: 1.3987x; 1.2706x over previous
//
#include <hip/hip_runtime.h>
#include <hip/hip_bf16.h>
#include <math.h>

typedef __attribute__((ext_vector_type(8))) short bf16x8;
typedef __attribute__((ext_vector_type(4))) short bf16x4;
typedef __attribute__((ext_vector_type(4))) float f32x4;

#define NB 4096
#define ND 1024
#define INV_T 14.2857142857142857f   // 1/0.07
#define WPITCH 136                   // bf16 elems: 272B rows, 16B aligned

__device__ inline unsigned short f2bf(float x) {
    __hip_bfloat16 h = __float2bfloat16(x);
    return *reinterpret_cast<unsigned short*>(&h);
}
__device__ inline float bf2f(unsigned short u) {
    unsigned v = ((unsigned)u) << 16;
    return __uint_as_float(v);
}
__device__ inline void gload16(const void* g, void* l) {
    __builtin_amdgcn_global_load_lds(
        (const __attribute__((address_space(1))) void*)g,
        (__attribute__((address_space(3))) void*)l, 16, 0, 0);
}

// ---------------- kernel 0: L2-normalize rows, cast to bf16 -----------------
__global__ __launch_bounds__(256) void norm_kernel(
        const float* __restrict__ M, const float* __restrict__ P,
        __hip_bfloat16* __restrict__ Mn, __hip_bfloat16* __restrict__ Pn) {
    int row = blockIdx.x & (NB - 1);
    const float* src = (blockIdx.x < NB) ? M : P;
    __hip_bfloat16* dst = (blockIdx.x < NB) ? Mn : Pn;
    int tid = threadIdx.x;
    float4 v = ((const float4*)(src + (size_t)row * ND))[tid];
    float ss = v.x * v.x + v.y * v.y + v.z * v.z + v.w * v.w;
    for (int off = 32; off; off >>= 1) ss += __shfl_down(ss, off);
    __shared__ float red[4];
    int lane = tid & 63, w = tid >> 6;
    if (lane == 0) red[w] = ss;
    __syncthreads();
    float rn = rsqrtf(red[0] + red[1] + red[2] + red[3]);
    ushort4 o;
    o.x = f2bf(v.x * rn); o.y = f2bf(v.y * rn);
    o.z = f2bf(v.z * rn); o.w = f2bf(v.w * rn);
    *(ushort4*)((unsigned short*)dst + (size_t)row * ND + tid * 4) = o;
}

// ---------------- kernel 1: per-row mask codes ------------------------------
__global__ __launch_bounds__(256) void key_kernel(
        const int* __restrict__ labels, const int* __restrict__ sm,
        const int* __restrict__ sp, int* __restrict__ code) {
    int i = blockIdx.x * 256 + threadIdx.x;
    if (i < NB) {
        int l = labels[i];
        code[i] = (l == 0) ? 0x40000000 : (1 + l + (sm[i] << 8) + (sp[i] << 16));
    }
}

// ------- kernel 2: fused row-sum + normalized masked weight matrix (bf16) ---
__global__ __launch_bounds__(256) void rowsumw_kernel(
        const float* __restrict__ cs, const int* __restrict__ code,
        unsigned short* __restrict__ W, float* __restrict__ flag) {
    int i = blockIdx.x;
    int ci = code[i];
    int tid = threadIdx.x;
    const float4* row = (const float4*)(cs + (size_t)i * NB);
    const int4* c4 = (const int4*)code;
    float4 v[4];
    int4 cj[4];
    float s = 0.f;
#pragma unroll
    for (int k = 0; k < 4; ++k) {
        int t = tid + k * 256;
        v[k] = row[t];
        cj[k] = c4[t];
        int j = t * 4;
        if (cj[k].x == ci && j + 0 != i) s += v[k].x;
        if (cj[k].y == ci && j + 1 != i) s += v[k].y;
        if (cj[k].z == ci && j + 2 != i) s += v[k].z;
        if (cj[k].w == ci && j + 3 != i) s += v[k].w;
    }
    for (int off = 1; off < 64; off <<= 1) s += __shfl_xor(s, off);
    __shared__ float red[4];
    int lane = tid & 63, w = tid >> 6;
    if (lane == 0) red[w] = s;
    __syncthreads();
    float tot = red[0] + red[1] + red[2] + red[3];
    float inv = (tot > 0.f) ? 1.f / tot : 0.f;
#pragma unroll
    for (int k = 0; k < 4; ++k) {
        int t = tid + k * 256;
        int j = t * 4;
        ushort4 o;
        o.x = (cj[k].x == ci && j + 0 != i) ? f2bf(v[k].x * inv) : (unsigned short)0;
        o.y = (cj[k].y == ci && j + 1 != i) ? f2bf(v[k].y * inv) : (unsigned short)0;
        o.z = (cj[k].z == ci && j + 2 != i) ? f2bf(v[k].z * inv) : (unsigned short)0;
        o.w = (cj[k].w == ci && j + 3 != i) ? f2bf(v[k].w * inv) : (unsigned short)0;
        *(ushort4*)&W[(size_t)i * NB + j] = o;
    }
    if (tid == 0) flag[i] = (tot > 0.f) ? 1.f : 0.f;
}

// ---------------- main-loop helper: 128x128 tile, swizzled gload_lds --------
__device__ inline void gemm_main(
        const __hip_bfloat16* __restrict__ A, const __hip_bfloat16* __restrict__ Bm,
        size_t rowBase, size_t colBase,
        __hip_bfloat16* sA, __hip_bfloat16* sB, f32x4 acc[4][4], int tid) {
    int lane = tid & 63, wid = tid >> 6;
    int wm = wid >> 1, wn = wid & 1;
    int lr = lane & 15, lg = lane >> 4;
    int lrow = lane >> 3;                 // 0..7 (= row&7 of the staged row)
    int lchunk = (lane & 7) ^ lrow;       // pre-swizzled global 16B chunk
    const __hip_bfloat16* gA = A + (rowBase + wid * 32 + lrow) * ND + lchunk * 8;
    const __hip_bfloat16* gB = Bm + (colBase + wid * 32 + lrow) * ND + lchunk * 8;
    int rxor = lr & 7;                    // read-side chunk xor (row&7)

    for (int kt = 0; kt < 16; ++kt) {
        int k0 = kt * 64;
#pragma unroll
        for (int c = 0; c < 4; ++c) {
            gload16(gA + (size_t)c * 8 * ND + k0, &sA[(wid * 4 + c) * 512]);
            gload16(gB + (size_t)c * 8 * ND + k0, &sB[(wid * 4 + c) * 512]);
        }
        __syncthreads();
#pragma unroll
        for (int ks = 0; ks < 2; ++ks) {
            bf16x8 av[4], bv[4];
            int coff = ((ks * 4 + lg) ^ rxor) * 8;
#pragma unroll
            for (int m = 0; m < 4; ++m)
                av[m] = *(const bf16x8*)&sA[(wm * 64 + m * 16 + lr) * 64 + coff];
#pragma unroll
            for (int n = 0; n < 4; ++n)
                bv[n] = *(const bf16x8*)&sB[(wn * 64 + n * 16 + lr) * 64 + coff];
#pragma unroll
            for (int m = 0; m < 4; ++m)
#pragma unroll
                for (int n = 0; n < 4; ++n)
                    acc[m][n] = __builtin_amdgcn_mfma_f32_16x16x32_bf16(
                        av[m], bv[n], acc[m][n], 0, 0, 0);
        }
        __syncthreads();
    }
}

// ---------------- kernel 3: GEMM + fused softmax/loss epilogue --------------
// SYM=0: S1 = Mn Pn^T, grid (32,32).  d1->dots[0], d2->dots[1],
//        rexp->rs0(rowsum1), cexp->colsum1.
// SYM=1: S = F F^T (F = Mn or Pn by blockIdx.y), upper-tri grid (528,2).
//        rexp->rowsum[row]; offdiag adds cexp->rowsum[col], d1+d2->dots[2+y].
template <int SYM>
__global__ __launch_bounds__(256, 2) void gemm_fused(
        const __hip_bfloat16* __restrict__ F0, const __hip_bfloat16* __restrict__ F1,
        const unsigned short* __restrict__ Wg,
        float* __restrict__ rs0, float* __restrict__ rs1,
        float* __restrict__ colsum, float* __restrict__ dots) {
    __shared__ char smem[WPITCH * 128 * 2];   // 34816 B
    __hip_bfloat16* sA = (__hip_bfloat16*)smem;
    __hip_bfloat16* sB = sA + 8192;
    unsigned short* wl = (unsigned short*)smem;

    int tid = threadIdx.x;
    int lane = tid & 63;
    int wid = tid >> 6;
    int wm = wid >> 1, wn = wid & 1;
    int lr = lane & 15, lg = lane >> 4;

    int bi, bj;
    const __hip_bfloat16 *A, *Bm;
    float* rowTgt;
    if (SYM == 0) {
        bi = blockIdx.y; bj = blockIdx.x;
        A = F0; Bm = F1; rowTgt = rs0;
    } else {
        int t = blockIdx.x;
        bi = 0;
        while (t >= 32 - bi) { t -= 32 - bi; ++bi; }
        bj = bi + t;
        A = blockIdx.y ? F1 : F0; Bm = A;
        rowTgt = blockIdx.y ? rs1 : rs0;
    }
    bool offdiag = (SYM != 0) && (bi != bj);
    bool doCol = (SYM == 0) || offdiag;
    size_t rowBase = (size_t)bi * 128;
    size_t colBase = (size_t)bj * 128;

    f32x4 acc[4][4] = {};
    gemm_main(A, Bm, rowBase, colBase, sA, sB, acc, tid);

    // ---- epilogue: stage W[i][j] tile ([il][jl], pitch WPITCH) ----
#pragma unroll
    for (int r8 = 0; r8 < 8; ++r8) {
        int il = r8 * 16 + (tid >> 4);
        int jl = (tid & 15) * 8;
        *(int4*)&wl[il * WPITCH + jl] =
            *(const int4*)&Wg[(rowBase + il) * (size_t)NB + colBase + jl];
    }
    __syncthreads();

    float d1 = 0.f, d2 = 0.f;
    float cexp[4] = {0.f, 0.f, 0.f, 0.f};
#pragma unroll
    for (int m = 0; m < 4; ++m) {
        float rexp[4] = {0.f, 0.f, 0.f, 0.f};
#pragma unroll
        for (int n = 0; n < 4; ++n) {
            int jl = wn * 64 + n * 16 + lr;
#pragma unroll
            for (int r = 0; r < 4; ++r) {
                int il = wm * 64 + m * 16 + lg * 4 + r;
                float sim = acc[m][n][r] * INV_T;
                float e = __expf(sim - INV_T);
                rexp[r] += e;
                cexp[n] += e;
                d1 += bf2f(wl[il * WPITCH + jl]) * sim;
            }
        }
#pragma unroll
        for (int r = 0; r < 4; ++r) {
            float v = rexp[r];
            v += __shfl_xor(v, 1); v += __shfl_xor(v, 2);
            v += __shfl_xor(v, 4); v += __shfl_xor(v, 8);
            if (lr == 0)
                atomicAdd(&rowTgt[rowBase + wm * 64 + m * 16 + lg * 4 + r], v);
        }
    }
    if (doCol) {
        float* ctgt = (SYM == 0) ? colsum : rowTgt;
#pragma unroll
        for (int n = 0; n < 4; ++n) {
            float v = cexp[n];
            v += __shfl_xor(v, 16); v += __shfl_xor(v, 32);
            if (lg == 0)
                atomicAdd(&ctgt[colBase + wn * 64 + n * 16 + lr], v);
        }
    }

    // ---- d2: stage W[j][i] tile ([jl][il], pitch WPITCH) ----
    if ((SYM == 0) || offdiag) {
        __syncthreads();
#pragma unroll
        for (int r8 = 0; r8 < 8; ++r8) {
            int jl = r8 * 16 + (tid >> 4);
            int il = (tid & 15) * 8;
            *(int4*)&wl[jl * WPITCH + il] =
                *(const int4*)&Wg[(colBase + jl) * (size_t)NB + rowBase + il];
        }
        __syncthreads();
#pragma unroll
        for (int m = 0; m < 4; ++m) {
            int il0 = wm * 64 + m * 16 + lg * 4;
#pragma unroll
            for (int n = 0; n < 4; ++n) {
                int jl = wn * 64 + n * 16 + lr;
                bf16x4 wv = *(const bf16x4*)&wl[jl * WPITCH + il0];
#pragma unroll
                for (int r = 0; r < 4; ++r)
                    d2 += bf2f((unsigned short)wv[r]) * (acc[m][n][r] * INV_T);
            }
        }
    }

    if (SYM == 0) {
        for (int off = 32; off; off >>= 1) {
            d1 += __shfl_xor(d1, off);
            d2 += __shfl_xor(d2, off);
        }
        if (lane == 0) {
            atomicAdd(&dots[0], d1);
            atomicAdd(&dots[1], d2);
        }
    } else {
        float dtot = d1 + (offdiag ? d2 : 0.f);
        for (int off = 32; off; off >>= 1) dtot += __shfl_xor(dtot, off);
        if (lane == 0) atomicAdd(&dots[2 + blockIdx.y], dtot);
    }
}

// ---------------- kernel 4: finalize --------------------------------------
__global__ __launch_bounds__(256) void finalize_kernel(
        const float* __restrict__ rowsum1, const float* __restrict__ colsum1,
        const float* __restrict__ rowsum3, const float* __restrict__ rowsum4,
        const float* __restrict__ flag, const float* __restrict__ dots,
        float* __restrict__ out) {
    int tid = threadIdx.x;
    float l = 0.f;
    for (int i = tid; i < NB; i += 256) {
        if (flag[i] != 0.f) {
            l += 4.f * INV_T + logf(rowsum1[i]) + logf(colsum1[i]) +
                 logf(rowsum3[i]) + logf(rowsum4[i]);
        }
    }
    for (int off = 32; off; off >>= 1) l += __shfl_down(l, off);
    __shared__ float red[4];
    int lane = tid & 63, w = tid >> 6;
    if (lane == 0) red[w] = l;
    __syncthreads();
    if (tid == 0) {
        float L = red[0] + red[1] + red[2] + red[3];
        float dt = dots[0] + dots[1] + dots[2] + dots[3];
        out[0] = (L - dt) / (4.0f * (float)NB);
    }
}

extern "C" void kernel_launch(void* const* d_in, const int* in_sizes, int n_in,
                              void* d_out, int out_size, void* d_ws, size_t ws_size,
                              hipStream_t stream) {
    const float* M = (const float*)d_in[0];
    const float* P = (const float*)d_in[1];
    const int* labels = (const int*)d_in[2];
    const int* sm = (const int*)d_in[3];
    const int* sp = (const int*)d_in[4];
    const float* cs = (const float*)d_in[5];
    float* out = (float*)d_out;

    char* ws = (char*)d_ws;
    __hip_bfloat16* Mn = (__hip_bfloat16*)ws;                              // 8 MB
    __hip_bfloat16* Pn = (__hip_bfloat16*)(ws + (size_t)8 * 1024 * 1024);  // 8 MB
    unsigned short* W = (unsigned short*)(ws + (size_t)16 * 1024 * 1024);  // 32 MB
    char* p = ws + (size_t)48 * 1024 * 1024;
    int* code = (int*)p;        p += 16384;
    float* flag = (float*)p;    p += 16384;
    float* rowsum1 = (float*)p; p += 16384;
    float* colsum1 = (float*)p; p += 16384;
    float* rowsum3 = (float*)p; p += 16384;
    float* rowsum4 = (float*)p; p += 16384;
    float* dots = (float*)p;

    // zero accumulators (rowsum1..colsum1..rowsum3..rowsum4..dots contiguous)
    hipMemsetAsync(rowsum1, 0, 4 * 16384 + 256, stream);

    norm_kernel<<<2 * NB, 256, 0, stream>>>(M, P, Mn, Pn);
    key_kernel<<<NB / 256, 256, 0, stream>>>(labels, sm, sp, code);
    rowsumw_kernel<<<NB, 256, 0, stream>>>(cs, code, W, flag);

    dim3 g0(32, 32);
    gemm_fused<0><<<g0, 256, 0, stream>>>(Mn, Pn, W, rowsum1, nullptr,
                                          colsum1, dots);
    dim3 g1(528, 2);
    gemm_fused<1><<<g1, 256, 0, stream>>>(Mn, Pn, W, rowsum3, rowsum4,
                                          nullptr, dots);

    finalize_kernel<<<1, 256, 0, stream>>>(rowsum1, colsum1, rowsum3, rowsum4,
                                           flag, dots, out);
}